// Round 6
// baseline (927.938 us; speedup 1.0000x reference)
//
#include <hip/hip_runtime.h>
#include <math.h>

#define NN 100000
#define NE 1600000
#define DIN 256
#define HD 64
#define OUTD 32
#define EMBD 128
#define SLOPE 0.2f
#define AST 68
#define NT ((NN + 63) / 64)
#define SCHUNK 1024
#define SNBLK ((NN + SCHUNK - 1) / SCHUNK)   // 98

__device__ __forceinline__ float lrelu(float x) { return x > 0.f ? x : SLOPE * x; }

// ================= CSR build =================
__global__ void k_count(const int* __restrict__ dst, int* __restrict__ cnt) {
    int i = blockIdx.x * blockDim.x + threadIdx.x;
    if (i < NE) atomicAdd(&cnt[dst[i]], 1);
}

__global__ __launch_bounds__(256) void k_scan1(const int* __restrict__ cnt,
                                               int* __restrict__ rowptr,
                                               int* __restrict__ blksum) {
    __shared__ int ts[256];
    int base = blockIdx.x * SCHUNK + threadIdx.x * 4;
    int v0 = 0, v1 = 0, v2 = 0, v3 = 0;
    if (base < NN)     v0 = cnt[base];
    if (base + 1 < NN) v1 = cnt[base + 1];
    if (base + 2 < NN) v2 = cnt[base + 2];
    if (base + 3 < NN) v3 = cnt[base + 3];
    int s = v0 + v1 + v2 + v3;
    ts[threadIdx.x] = s;
    __syncthreads();
    for (int off = 1; off < 256; off <<= 1) {
        int w = (threadIdx.x >= off) ? ts[threadIdx.x - off] : 0;
        __syncthreads();
        ts[threadIdx.x] += w;
        __syncthreads();
    }
    int excl = ts[threadIdx.x] - s;
    if (base < NN)     rowptr[base]     = excl;
    if (base + 1 < NN) rowptr[base + 1] = excl + v0;
    if (base + 2 < NN) rowptr[base + 2] = excl + v0 + v1;
    if (base + 3 < NN) rowptr[base + 3] = excl + v0 + v1 + v2;
    if (threadIdx.x == 255) blksum[blockIdx.x] = ts[255];
}

__global__ __launch_bounds__(128) void k_scan2(int* __restrict__ blksum) {
    __shared__ int ts[128];
    int t = threadIdx.x;
    int v = (t < SNBLK) ? blksum[t] : 0;
    ts[t] = v;
    __syncthreads();
    for (int off = 1; off < 128; off <<= 1) {
        int w = (t >= off) ? ts[t - off] : 0;
        __syncthreads();
        ts[t] += w;
        __syncthreads();
    }
    if (t < SNBLK) blksum[t] = ts[t] - v;
}

__global__ void k_scan3(const int* __restrict__ blksum, const int* __restrict__ cnt,
                        int* __restrict__ rowptr, int* __restrict__ cursor,
                        float* __restrict__ invdeg) {
    int i = blockIdx.x * blockDim.x + threadIdx.x;
    if (i < NN) {
        int v = rowptr[i] + blksum[i >> 10];
        rowptr[i] = v;
        cursor[i] = v;
        invdeg[i] = 1.0f / fmaxf((float)cnt[i], 1.0f);
    }
    if (i == 0) rowptr[NN] = NE;
}

__global__ void k_fill(const int* __restrict__ src, const int* __restrict__ dst,
                       int* __restrict__ cursor, int* __restrict__ colsrc) {
    int i = blockIdx.x * blockDim.x + threadIdx.x;
    if (i >= NE) return;
    int pos = atomicAdd(&cursor[dst[i]], 1);
    colsrc[pos] = src[i];
}

// ================= tiled GEMM helpers =================
__device__ __forceinline__ void stageA(const float* __restrict__ g, int nbase, int ldg, int koff,
                                       float (*As)[AST]) {
    for (int i = threadIdx.x; i < 1024; i += 256) {
        int m = i >> 4, k4 = (i & 15) << 2;
        int row = nbase + m;
        if (row >= NN) row = NN - 1;
        float4 v = *(const float4*)&g[(size_t)row * ldg + koff + k4];
        *(float4*)&As[m][k4] = v;
    }
}
__device__ __forceinline__ void stageW(const float* __restrict__ g, float* Ws) {
    for (int i = threadIdx.x; i < 1024; i += 256) ((float4*)Ws)[i] = ((const float4*)g)[i];
}
__device__ __forceinline__ void stageWcols(const float* __restrict__ g, int ldg, int coff,
                                           float* Ws) {
    for (int i = threadIdx.x; i < 1024; i += 256) {
        int r = i >> 4, c4 = (i & 15) << 2;
        *(float4*)&Ws[r * 64 + c4] = *(const float4*)&g[r * ldg + coff + c4];
    }
}

// acc[4][4] += A[tr*4+i][k] * W[k][tc*4+j], A read as float4 (AST=68 keeps alignment)
__device__ __forceinline__ void mac16v(const float (*As)[AST], const float* __restrict__ Ws,
                                       float (*acc)[4], int tr, int tc) {
#pragma unroll 4
    for (int k4 = 0; k4 < 64; k4 += 4) {
        float4 a0 = *(const float4*)&As[tr * 4 + 0][k4];
        float4 a1 = *(const float4*)&As[tr * 4 + 1][k4];
        float4 a2 = *(const float4*)&As[tr * 4 + 2][k4];
        float4 a3 = *(const float4*)&As[tr * 4 + 3][k4];
#pragma unroll
        for (int j = 0; j < 4; j++) {
            float4 w = *(const float4*)&Ws[(k4 + j) * 64 + tc * 4];
            float e0 = (&a0.x)[j], e1 = (&a1.x)[j], e2 = (&a2.x)[j], e3 = (&a3.x)[j];
            acc[0][0] += e0 * w.x; acc[0][1] += e0 * w.y; acc[0][2] += e0 * w.z; acc[0][3] += e0 * w.w;
            acc[1][0] += e1 * w.x; acc[1][1] += e1 * w.y; acc[1][2] += e1 * w.z; acc[1][3] += e1 * w.w;
            acc[2][0] += e2 * w.x; acc[2][1] += e2 * w.y; acc[2][2] += e2 * w.z; acc[2][3] += e2 * w.w;
            acc[3][0] += e3 * w.x; acc[3][1] += e3 * w.y; acc[3][2] += e3 * w.z; acc[3][3] += e3 * w.w;
        }
    }
}

// dual-W: share A loads across two weight matrices
__device__ __forceinline__ void mac16v2(const float (*As)[AST], const float* __restrict__ W0,
                                        const float* __restrict__ W1, float (*accA)[4],
                                        float (*accB)[4], int tr, int tc) {
#pragma unroll 2
    for (int k4 = 0; k4 < 64; k4 += 4) {
        float4 a0 = *(const float4*)&As[tr * 4 + 0][k4];
        float4 a1 = *(const float4*)&As[tr * 4 + 1][k4];
        float4 a2 = *(const float4*)&As[tr * 4 + 2][k4];
        float4 a3 = *(const float4*)&As[tr * 4 + 3][k4];
#pragma unroll
        for (int j = 0; j < 4; j++) {
            float e0 = (&a0.x)[j], e1 = (&a1.x)[j], e2 = (&a2.x)[j], e3 = (&a3.x)[j];
            float4 w = *(const float4*)&W0[(k4 + j) * 64 + tc * 4];
            accA[0][0] += e0 * w.x; accA[0][1] += e0 * w.y; accA[0][2] += e0 * w.z; accA[0][3] += e0 * w.w;
            accA[1][0] += e1 * w.x; accA[1][1] += e1 * w.y; accA[1][2] += e1 * w.z; accA[1][3] += e1 * w.w;
            accA[2][0] += e2 * w.x; accA[2][1] += e2 * w.y; accA[2][2] += e2 * w.z; accA[2][3] += e2 * w.w;
            accA[3][0] += e3 * w.x; accA[3][1] += e3 * w.y; accA[3][2] += e3 * w.z; accA[3][3] += e3 * w.w;
            float4 u = *(const float4*)&W1[(k4 + j) * 64 + tc * 4];
            accB[0][0] += e0 * u.x; accB[0][1] += e0 * u.y; accB[0][2] += e0 * u.z; accB[0][3] += e0 * u.w;
            accB[1][0] += e1 * u.x; accB[1][1] += e1 * u.y; accB[1][2] += e1 * u.z; accB[1][3] += e1 * u.w;
            accB[2][0] += e2 * u.x; accB[2][1] += e2 * u.y; accB[2][2] += e2 * u.z; accB[2][3] += e2 * u.w;
            accB[3][0] += e3 * u.x; accB[3][1] += e3 * u.y; accB[3][2] += e3 * u.z; accB[3][3] += e3 * u.w;
        }
    }
}

// ================= fused front (n2vp computed in-kernel, never hits global) =================
__global__ __launch_bounds__(256) void k_front_t(const float* __restrict__ x,
                                                 const float* __restrict__ n2v,
                                                 const float* __restrict__ n2v_w,
                                                 const float* __restrict__ n2v_b,
                                                 const float* __restrict__ ip_w,
                                                 const float* __restrict__ ip_b,
                                                 const float* __restrict__ gate_w,
                                                 const float* __restrict__ gate_b,
                                                 float* __restrict__ h0) {
    __shared__ float As[64][AST];
    __shared__ float W0[4096];
    __shared__ float W1[4096];
    int nbase = blockIdx.x * 64;
    int tc = threadIdx.x & 15, tr = threadIdx.x >> 4;

    // --- n2vp = n2v @ n2v_w + b (accumulate into araw, then park in As) ---
    float araw[4][4] = {};
    for (int c = 0; c < 2; c++) {
        stageA(n2v, nbase, EMBD, c * 64, As);
        stageW(n2v_w + c * 4096, W0);
        __syncthreads();
        mac16v(As, W0, araw, tr, tc);
        __syncthreads();
    }
    {
        float b0 = n2v_b[tc * 4], b1 = n2v_b[tc * 4 + 1], b2 = n2v_b[tc * 4 + 2], b3 = n2v_b[tc * 4 + 3];
#pragma unroll
        for (int i = 0; i < 4; i++) {
            float4 o = {araw[i][0] + b0, araw[i][1] + b1, araw[i][2] + b2, araw[i][3] + b3};
            *(float4*)&As[tr * 4 + i][tc * 4] = o;
            araw[i][0] = araw[i][1] = araw[i][2] = araw[i][3] = 0.f;
        }
    }
    // --- tails: adel = n2vp @ ip_w[256:], ag = n2vp @ gate_w[256:] ---
    float ag[4][4] = {}, adel[4][4] = {};
    stageW(ip_w + DIN * 64, W0);
    stageW(gate_w + DIN * 64, W1);
    __syncthreads();
    mac16v2(As, W0, W1, adel, ag, tr, tc);
    __syncthreads();
    // --- x chunks: araw += x@ip_w[:256], ag += x@gate_w[:256] ---
    for (int c = 0; c < 4; c++) {
        stageA(x, nbase, DIN, c * 64, As);
        stageW(ip_w + c * 4096, W0);
        stageW(gate_w + c * 4096, W1);
        __syncthreads();
        mac16v2(As, W0, W1, araw, ag, tr, tc);
        __syncthreads();
    }

    float ib0 = ip_b[tc * 4], ib1 = ip_b[tc * 4 + 1], ib2 = ip_b[tc * 4 + 2], ib3 = ip_b[tc * 4 + 3];
    float gb0 = gate_b[tc * 4], gb1 = gate_b[tc * 4 + 1], gb2 = gate_b[tc * 4 + 2], gb3 = gate_b[tc * 4 + 3];
#pragma unroll
    for (int i = 0; i < 4; i++) {
        int row = nbase + tr * 4 + i;
        if (row < NN) {
            float r0 = araw[i][0] + ib0, r1 = araw[i][1] + ib1, r2 = araw[i][2] + ib2, r3 = araw[i][3] + ib3;
            float s0 = 1.f / (1.f + __expf(-(ag[i][0] + gb0)));
            float s1 = 1.f / (1.f + __expf(-(ag[i][1] + gb1)));
            float s2 = 1.f / (1.f + __expf(-(ag[i][2] + gb2)));
            float s3 = 1.f / (1.f + __expf(-(ag[i][3] + gb3)));
            float4 o = {r0 + s0 * adel[i][0], r1 + s1 * adel[i][1],
                        r2 + s2 * adel[i][2], r3 + s3 * adel[i][3]};
            *(float4*)&h0[(size_t)row * HD + tc * 4] = o;
        }
    }
}

// ================= gather mean =================
__global__ void k_gather_mean(const int* __restrict__ rowptr, const int* __restrict__ colsrc,
                              const float* __restrict__ invdeg, const float* __restrict__ hin,
                              float* __restrict__ agg) {
    int t = threadIdx.x & 63;
    int gw = blockIdx.x * (blockDim.x >> 6) + (threadIdx.x >> 6);
    int stride = gridDim.x * (blockDim.x >> 6);
    for (int n = gw; n < NN; n += stride) {
        int bg = rowptr[n], en = rowptr[n + 1];
        float acc = 0.f;
        int i = bg;
        for (; i + 4 <= en; i += 4) {
            int s0 = colsrc[i], s1 = colsrc[i + 1], s2 = colsrc[i + 2], s3 = colsrc[i + 3];
            acc += hin[(size_t)s0 * HD + t] + hin[(size_t)s1 * HD + t] +
                   hin[(size_t)s2 * HD + t] + hin[(size_t)s3 * HD + t];
        }
        for (; i < en; i++) acc += hin[(size_t)colsrc[i] * HD + t];
        agg[(size_t)n * HD + t] = acc * invdeg[n];
    }
}

// ================= SAGE combine (dual-W resident) =================
__global__ __launch_bounds__(256) void k_sage_t(const float* __restrict__ agg,
                                                const float* __restrict__ h,
                                                const float* __restrict__ wl,
                                                const float* __restrict__ bl,
                                                const float* __restrict__ wr,
                                                float* __restrict__ hout) {
    __shared__ float As[64][AST];
    __shared__ float W0[4096];
    __shared__ float W1[4096];
    int nbase = blockIdx.x * 64;
    int tc = threadIdx.x & 15, tr = threadIdx.x >> 4;
    float acc[4][4] = {};
    stageA(agg, nbase, HD, 0, As);
    stageW(wl, W0);
    stageW(wr, W1);
    __syncthreads();
    mac16v(As, W0, acc, tr, tc);
    __syncthreads();
    stageA(h, nbase, HD, 0, As);
    __syncthreads();
    mac16v(As, W1, acc, tr, tc);
    float b0 = bl[tc * 4], b1 = bl[tc * 4 + 1], b2 = bl[tc * 4 + 2], b3 = bl[tc * 4 + 3];
#pragma unroll
    for (int i = 0; i < 4; i++) {
        int row = nbase + tr * 4 + i;
        if (row < NN) {
            float4 o = {fmaxf(acc[i][0] + b0, 0.f), fmaxf(acc[i][1] + b1, 0.f),
                        fmaxf(acc[i][2] + b2, 0.f), fmaxf(acc[i][3] + b3, 0.f)};
            *(float4*)&hout[(size_t)row * HD + tc * 4] = o;
        }
    }
}

// ================= GAT transform (both head-halves resident) =================
__global__ __launch_bounds__(256) void k_gatxh_t(const float* __restrict__ h,
                                                 const float* __restrict__ w,
                                                 const float* __restrict__ att_s,
                                                 const float* __restrict__ att_d,
                                                 float* __restrict__ xh,
                                                 float* __restrict__ a_s,
                                                 float* __restrict__ a_d) {
    __shared__ float As[64][AST];
    __shared__ float W0[4096];
    __shared__ float W1[4096];
    int nbase = blockIdx.x * 64;
    int tc = threadIdx.x & 15, tr = threadIdx.x >> 4;
    float acc0[4][4] = {}, acc1[4][4] = {};
    stageA(h, nbase, HD, 0, As);
    stageWcols(w, 128, 0, W0);
    stageWcols(w, 128, 64, W1);
    __syncthreads();
    mac16v2(As, W0, W1, acc0, acc1, tr, tc);
#pragma unroll
    for (int half = 0; half < 2; half++) {
        float(*acc)[4] = half ? acc1 : acc0;
        float as0 = att_s[half * 64 + tc * 4], as1 = att_s[half * 64 + tc * 4 + 1];
        float as2 = att_s[half * 64 + tc * 4 + 2], as3 = att_s[half * 64 + tc * 4 + 3];
        float ad0 = att_d[half * 64 + tc * 4], ad1 = att_d[half * 64 + tc * 4 + 1];
        float ad2 = att_d[half * 64 + tc * 4 + 2], ad3 = att_d[half * 64 + tc * 4 + 3];
#pragma unroll
        for (int i = 0; i < 4; i++) {
            int row = nbase + tr * 4 + i;
            float ps = acc[i][0] * as0 + acc[i][1] * as1 + acc[i][2] * as2 + acc[i][3] * as3;
            float pd = acc[i][0] * ad0 + acc[i][1] * ad1 + acc[i][2] * ad2 + acc[i][3] * ad3;
#pragma unroll
            for (int off = 8; off; off >>= 1) {
                ps += __shfl_xor(ps, off);
                pd += __shfl_xor(pd, off);
            }
            if (row < NN) {
                *(float4*)&xh[(size_t)row * 128 + half * 64 + tc * 4] = *(float4*)&acc[i][0];
                if (tc == 0) {
                    a_s[row * 2 + half] = ps;
                    a_d[row * 2 + half] = pd;
                }
            }
        }
    }
}

// ================= GAT fused softmax-gather (2 passes: max, then sum+PV) =================
__global__ void k_gat_fused(const int* __restrict__ rowptr, const int* __restrict__ colsrc,
                            const float* __restrict__ a_s, const float* __restrict__ a_d,
                            const float* __restrict__ xh, const float* __restrict__ gb,
                            float* __restrict__ hout) {
    int t = threadIdx.x & 63;
    float bias = gb[t];
    int gw = blockIdx.x * (blockDim.x >> 6) + (threadIdx.x >> 6);
    int stride = gridDim.x * (blockDim.x >> 6);
    for (int n = gw; n < NN; n += stride) {
        int bg = rowptr[n], en = rowptr[n + 1];
        float ad0 = a_d[n * 2], ad1 = a_d[n * 2 + 1];
        float self0 = lrelu(a_s[n * 2] + ad0);
        float self1 = lrelu(a_s[n * 2 + 1] + ad1);
        // pass A: max (lane-parallel)
        float m0 = self0, m1 = self1;
        for (int i = bg + t; i < en; i += 64) {
            int s = colsrc[i];
            m0 = fmaxf(m0, lrelu(a_s[s * 2] + ad0));
            m1 = fmaxf(m1, lrelu(a_s[s * 2 + 1] + ad1));
        }
#pragma unroll
        for (int off = 32; off; off >>= 1) {
            m0 = fmaxf(m0, __shfl_xor(m0, off));
            m1 = fmaxf(m1, __shfl_xor(m1, off));
        }
        // pass B: fused exp-sum + weighted gather (per-head accumulators)
        float ws0 = __expf(self0 - m0), ws1 = __expf(self1 - m1);
        float s0 = ws0, s1 = ws1;
        float acc0 = ws0 * xh[(size_t)n * 128 + t];
        float acc1 = ws1 * xh[(size_t)n * 128 + 64 + t];
        int i = bg;
        for (; i + 2 <= en; i += 2) {
            int sa = colsrc[i], sb = colsrc[i + 1];
            float wa0 = __expf(lrelu(a_s[sa * 2] + ad0) - m0);
            float wa1 = __expf(lrelu(a_s[sa * 2 + 1] + ad1) - m1);
            float wb0 = __expf(lrelu(a_s[sb * 2] + ad0) - m0);
            float wb1 = __expf(lrelu(a_s[sb * 2 + 1] + ad1) - m1);
            float xa0 = xh[(size_t)sa * 128 + t], xa1 = xh[(size_t)sa * 128 + 64 + t];
            float xb0 = xh[(size_t)sb * 128 + t], xb1 = xh[(size_t)sb * 128 + 64 + t];
            s0 += wa0 + wb0;
            s1 += wa1 + wb1;
            acc0 += wa0 * xa0 + wb0 * xb0;
            acc1 += wa1 * xa1 + wb1 * xb1;
        }
        for (; i < en; i++) {
            int s = colsrc[i];
            float w0 = __expf(lrelu(a_s[s * 2] + ad0) - m0);
            float w1 = __expf(lrelu(a_s[s * 2 + 1] + ad1) - m1);
            s0 += w0;
            s1 += w1;
            acc0 += w0 * xh[(size_t)s * 128 + t];
            acc1 += w1 * xh[(size_t)s * 128 + 64 + t];
        }
        float r0 = 0.5f / (s0 + 1e-16f), r1 = 0.5f / (s1 + 1e-16f);
        hout[(size_t)n * HD + t] = fmaxf(acc0 * r0 + acc1 * r1 + bias, 0.f);
    }
}

// ================= final SAGE =================
__global__ void k_pfin(const float* __restrict__ h, const float* __restrict__ wl,
                       float* __restrict__ P) {
    __shared__ float sw[HD * OUTD];
    for (int i = threadIdx.x; i < HD * OUTD; i += blockDim.x) sw[i] = wl[i];
    __syncthreads();
    int t = threadIdx.x & 63;
    int c = t & 31, half = t >> 5;
    int gw = blockIdx.x * (blockDim.x >> 6) + (threadIdx.x >> 6);
    int stride = gridDim.x * (blockDim.x >> 6);
    for (int n = gw; n < NN; n += stride) {
        float hv = h[(size_t)n * HD + t];
        float acc = 0.f;
#pragma unroll 8
        for (int i = 0; i < 32; i++) {
            float bb = __shfl(hv, half * 32 + i);
            acc += bb * sw[half * 1024 + i * 32 + c];
        }
        acc += __shfl_xor(acc, 32);
        if (half == 0) P[(size_t)n * OUTD + c] = acc;
    }
}

__global__ void k_final_fused(const int* __restrict__ rowptr, const int* __restrict__ colsrc,
                              const float* __restrict__ invdeg, const float* __restrict__ P,
                              const float* __restrict__ h, const float* __restrict__ bl,
                              const float* __restrict__ wr, float* __restrict__ out) {
    __shared__ float sw[HD * OUTD];
    for (int i = threadIdx.x; i < HD * OUTD; i += blockDim.x) sw[i] = wr[i];
    __syncthreads();
    int t = threadIdx.x & 63;
    int j = t & 31, half = t >> 5;
    float bias = bl[j];
    int gw = blockIdx.x * (blockDim.x >> 6) + (threadIdx.x >> 6);
    int stride = gridDim.x * (blockDim.x >> 6);
    for (int n = gw; n < NN; n += stride) {
        int bg = rowptr[n], en = rowptr[n + 1];
        float acc = 0.f;
        for (int i = bg + half; i < en; i += 2) acc += P[(size_t)colsrc[i] * OUTD + j];
        acc += __shfl_xor(acc, 32);
        float hv = h[(size_t)n * HD + t];
        float o = 0.f;
#pragma unroll 8
        for (int i2 = 0; i2 < 32; i2++) {
            float bb = __shfl(hv, half * 32 + i2);
            o += bb * sw[half * 1024 + i2 * 32 + j];
        }
        o += __shfl_xor(o, 32);
        if (half == 0) out[(size_t)n * OUTD + j] = acc * invdeg[n] + bias + o;
    }
}

// ================= launch =================
extern "C" void kernel_launch(void* const* d_in, const int* in_sizes, int n_in,
                              void* d_out, int out_size, void* d_ws, size_t ws_size,
                              hipStream_t stream) {
    const float* x      = (const float*)d_in[0];
    const int*   eidx   = (const int*)d_in[1];
    const float* n2v    = (const float*)d_in[2];
    const float* n2v_w  = (const float*)d_in[3];
    const float* n2v_b  = (const float*)d_in[4];
    const float* ip_w   = (const float*)d_in[5];
    const float* ip_b   = (const float*)d_in[6];
    const float* gate_w = (const float*)d_in[7];
    const float* gate_b = (const float*)d_in[8];
    const float* s0_wl  = (const float*)d_in[9];
    const float* s0_bl  = (const float*)d_in[10];
    const float* s0_wr  = (const float*)d_in[11];
    const float* s1_wl  = (const float*)d_in[12];
    const float* s1_bl  = (const float*)d_in[13];
    const float* s1_wr  = (const float*)d_in[14];
    const float* gat_w  = (const float*)d_in[15];
    const float* att_s  = (const float*)d_in[16];
    const float* att_d  = (const float*)d_in[17];
    const float* gat_b  = (const float*)d_in[18];
    const float* f_wl   = (const float*)d_in[19];
    const float* f_bl   = (const float*)d_in[20];
    const float* f_wr   = (const float*)d_in[21];

    const int* src = eidx;
    const int* dst = eidx + NE;

    // ---- workspace ----
    float* ws     = (float*)d_ws;
    float* invdeg = ws;                        // N
    float* S1     = invdeg + NN;               // 64N
    float* S2     = S1 + (size_t)NN * HD;      // 64N
    float* S4     = S2 + (size_t)NN * HD;      // 128N
    float* a_s    = S4 + (size_t)NN * 128;     // 2N
    float* a_d    = a_s + (size_t)NN * 2;      // 2N
    float* P      = a_d + (size_t)NN * 2;      // 32N
    int*   cnt    = (int*)(P + (size_t)NN * OUTD);
    int*   rowptr = cnt + NN;
    int*   cursor = rowptr + NN + 1;
    int*   blksum = cursor + NN;               // 128
    int*   colsrc = blksum + 128;              // NE

    float* agg = S4;
    float* xh  = S4;
    float* out = (float*)d_out;

    const int BT = 256;
    dim3 b128(128), b256(BT);
    int eblk = (NE + BT - 1) / BT;
    int nblk = (NN + BT - 1) / BT;

    // ---- CSR ----
    hipMemsetAsync(cnt, 0, (size_t)NN * 4, stream);
    k_count<<<eblk, b256, 0, stream>>>(dst, cnt);
    k_scan1<<<SNBLK, b256, 0, stream>>>(cnt, rowptr, blksum);
    k_scan2<<<1, b128, 0, stream>>>(blksum);
    k_scan3<<<nblk, b256, 0, stream>>>(blksum, cnt, rowptr, cursor, invdeg);
    k_fill<<<eblk, b256, 0, stream>>>(src, dst, cursor, colsrc);

    // ---- front (n2vp fused) ----
    k_front_t<<<NT, b256, 0, stream>>>(x, n2v, n2v_w, n2v_b, ip_w, ip_b, gate_w, gate_b, S2);

    // ---- SAGE 0: S2 -> S1 ----
    k_gather_mean<<<2048, b256, 0, stream>>>(rowptr, colsrc, invdeg, S2, agg);
    k_sage_t<<<NT, b256, 0, stream>>>(agg, S2, s0_wl, s0_bl, s0_wr, S1);

    // ---- SAGE 1: S1 -> S2 ----
    k_gather_mean<<<2048, b256, 0, stream>>>(rowptr, colsrc, invdeg, S1, agg);
    k_sage_t<<<NT, b256, 0, stream>>>(agg, S1, s1_wl, s1_bl, s1_wr, S2);

    // ---- GAT: S2 -> S1 ----
    k_gatxh_t<<<NT, b256, 0, stream>>>(S2, gat_w, att_s, att_d, xh, a_s, a_d);
    k_gat_fused<<<2048, b256, 0, stream>>>(rowptr, colsrc, a_s, a_d, xh, gat_b, S1);

    // ---- final SAGE: S1 -> out ----
    k_pfin<<<2048, b256, 0, stream>>>(S1, f_wl, P);
    k_final_fused<<<2048, b256, 0, stream>>>(rowptr, colsrc, invdeg, P, S1, f_bl, f_wr, out);
}

// Round 8
// 906.611 us; speedup vs baseline: 1.0235x; 1.0235x over previous
//
#include <hip/hip_runtime.h>
#include <math.h>

#define NN 100000
#define NE 1600000
#define DIN 256
#define HD 64
#define OUTD 32
#define EMBD 128
#define SLOPE 0.2f
#define AST2 36
#define NT ((NN + 63) / 64)
#define SCHUNK 1024
#define SNBLK ((NN + SCHUNK - 1) / SCHUNK)   // 98

__device__ __forceinline__ float lrelu(float x) { return x > 0.f ? x : SLOPE * x; }

// ================= CSR build =================
__global__ void k_count(const int* __restrict__ dst, int* __restrict__ cnt) {
    int i = blockIdx.x * blockDim.x + threadIdx.x;
    if (i < NE) atomicAdd(&cnt[dst[i]], 1);
}

__global__ __launch_bounds__(256) void k_scan1(const int* __restrict__ cnt,
                                               int* __restrict__ rowptr,
                                               int* __restrict__ blksum) {
    __shared__ int ts[256];
    int base = blockIdx.x * SCHUNK + threadIdx.x * 4;
    int v0 = 0, v1 = 0, v2 = 0, v3 = 0;
    if (base < NN)     v0 = cnt[base];
    if (base + 1 < NN) v1 = cnt[base + 1];
    if (base + 2 < NN) v2 = cnt[base + 2];
    if (base + 3 < NN) v3 = cnt[base + 3];
    int s = v0 + v1 + v2 + v3;
    ts[threadIdx.x] = s;
    __syncthreads();
    for (int off = 1; off < 256; off <<= 1) {
        int w = (threadIdx.x >= off) ? ts[threadIdx.x - off] : 0;
        __syncthreads();
        ts[threadIdx.x] += w;
        __syncthreads();
    }
    int excl = ts[threadIdx.x] - s;
    if (base < NN)     rowptr[base]     = excl;
    if (base + 1 < NN) rowptr[base + 1] = excl + v0;
    if (base + 2 < NN) rowptr[base + 2] = excl + v0 + v1;
    if (base + 3 < NN) rowptr[base + 3] = excl + v0 + v1 + v2;
    if (threadIdx.x == 255) blksum[blockIdx.x] = ts[255];
}

__global__ __launch_bounds__(128) void k_scan2(int* __restrict__ blksum) {
    __shared__ int ts[128];
    int t = threadIdx.x;
    int v = (t < SNBLK) ? blksum[t] : 0;
    ts[t] = v;
    __syncthreads();
    for (int off = 1; off < 128; off <<= 1) {
        int w = (t >= off) ? ts[t - off] : 0;
        __syncthreads();
        ts[t] += w;
        __syncthreads();
    }
    if (t < SNBLK) blksum[t] = ts[t] - v;
}

__global__ void k_scan3(const int* __restrict__ blksum, const int* __restrict__ cnt,
                        int* __restrict__ rowptr, int* __restrict__ cursor,
                        float* __restrict__ invdeg) {
    int i = blockIdx.x * blockDim.x + threadIdx.x;
    if (i < NN) {
        int v = rowptr[i] + blksum[i >> 10];
        rowptr[i] = v;
        cursor[i] = v;
        invdeg[i] = 1.0f / fmaxf((float)cnt[i], 1.0f);
    }
    if (i == 0) rowptr[NN] = NE;
}

__global__ void k_fill(const int* __restrict__ src, const int* __restrict__ dst,
                       int* __restrict__ cursor, int* __restrict__ colsrc) {
    int i = blockIdx.x * blockDim.x + threadIdx.x;
    if (i >= NE) return;
    int pos = atomicAdd(&cursor[dst[i]], 1);
    colsrc[pos] = src[i];
}

// ================= tiled GEMM helpers (K-chunk = 32, small LDS) =================
// stage 64 rows x 32 cols of A
__device__ __forceinline__ void stageA32(const float* __restrict__ g, int nbase, int ldg,
                                         int koff, float (*As)[AST2]) {
    for (int i = threadIdx.x; i < 512; i += 256) {
        int m = i >> 3, k4 = (i & 7) << 2;
        int row = nbase + m;
        if (row >= NN) row = NN - 1;
        *(float4*)&As[m][k4] = *(const float4*)&g[(size_t)row * ldg + koff + k4];
    }
}
// stage 32x64 contiguous W panel
__device__ __forceinline__ void stageW32(const float* __restrict__ g, float* Ws) {
    for (int i = threadIdx.x; i < 512; i += 256) ((float4*)Ws)[i] = ((const float4*)g)[i];
}
// stage 32 rows x 64 cols from row-major [32+][ldg] with col offset
__device__ __forceinline__ void stageW32cols(const float* __restrict__ g, int ldg, int coff,
                                             float* Ws) {
    for (int i = threadIdx.x; i < 512; i += 256) {
        int r = i >> 4, c4 = (i & 15) << 2;   // 32 rows x 16 float4/row  (FIXED)
        *(float4*)&Ws[r * 64 + c4] = *(const float4*)&g[r * ldg + coff + c4];
    }
}

// acc[4][4] += A[tr*4+i][k] * W[k][tc*4+j], k in [0,32)
__device__ __forceinline__ void mac8v(const float (*As)[AST2], const float* __restrict__ Ws,
                                      float (*acc)[4], int tr, int tc) {
#pragma unroll
    for (int k4 = 0; k4 < 32; k4 += 4) {
        float4 a0 = *(const float4*)&As[tr * 4 + 0][k4];
        float4 a1 = *(const float4*)&As[tr * 4 + 1][k4];
        float4 a2 = *(const float4*)&As[tr * 4 + 2][k4];
        float4 a3 = *(const float4*)&As[tr * 4 + 3][k4];
#pragma unroll
        for (int j = 0; j < 4; j++) {
            float4 w = *(const float4*)&Ws[(k4 + j) * 64 + tc * 4];
            float e0 = (&a0.x)[j], e1 = (&a1.x)[j], e2 = (&a2.x)[j], e3 = (&a3.x)[j];
            acc[0][0] += e0 * w.x; acc[0][1] += e0 * w.y; acc[0][2] += e0 * w.z; acc[0][3] += e0 * w.w;
            acc[1][0] += e1 * w.x; acc[1][1] += e1 * w.y; acc[1][2] += e1 * w.z; acc[1][3] += e1 * w.w;
            acc[2][0] += e2 * w.x; acc[2][1] += e2 * w.y; acc[2][2] += e2 * w.z; acc[2][3] += e2 * w.w;
            acc[3][0] += e3 * w.x; acc[3][1] += e3 * w.y; acc[3][2] += e3 * w.z; acc[3][3] += e3 * w.w;
        }
    }
}

// dual-W over the same A chunk
__device__ __forceinline__ void mac8v2(const float (*As)[AST2], const float* __restrict__ W0,
                                       const float* __restrict__ W1, float (*accA)[4],
                                       float (*accB)[4], int tr, int tc) {
#pragma unroll
    for (int k4 = 0; k4 < 32; k4 += 4) {
        float4 a0 = *(const float4*)&As[tr * 4 + 0][k4];
        float4 a1 = *(const float4*)&As[tr * 4 + 1][k4];
        float4 a2 = *(const float4*)&As[tr * 4 + 2][k4];
        float4 a3 = *(const float4*)&As[tr * 4 + 3][k4];
#pragma unroll
        for (int j = 0; j < 4; j++) {
            float e0 = (&a0.x)[j], e1 = (&a1.x)[j], e2 = (&a2.x)[j], e3 = (&a3.x)[j];
            float4 w = *(const float4*)&W0[(k4 + j) * 64 + tc * 4];
            accA[0][0] += e0 * w.x; accA[0][1] += e0 * w.y; accA[0][2] += e0 * w.z; accA[0][3] += e0 * w.w;
            accA[1][0] += e1 * w.x; accA[1][1] += e1 * w.y; accA[1][2] += e1 * w.z; accA[1][3] += e1 * w.w;
            accA[2][0] += e2 * w.x; accA[2][1] += e2 * w.y; accA[2][2] += e2 * w.z; accA[2][3] += e2 * w.w;
            accA[3][0] += e3 * w.x; accA[3][1] += e3 * w.y; accA[3][2] += e3 * w.z; accA[3][3] += e3 * w.w;
            float4 u = *(const float4*)&W1[(k4 + j) * 64 + tc * 4];
            accB[0][0] += e0 * u.x; accB[0][1] += e0 * u.y; accB[0][2] += e0 * u.z; accB[0][3] += e0 * u.w;
            accB[1][0] += e1 * u.x; accB[1][1] += e1 * u.y; accB[1][2] += e1 * u.z; accB[1][3] += e1 * u.w;
            accB[2][0] += e2 * u.x; accB[2][1] += e2 * u.y; accB[2][2] += e2 * u.z; accB[2][3] += e2 * u.w;
            accB[3][0] += e3 * u.x; accB[3][1] += e3 * u.y; accB[3][2] += e3 * u.z; accB[3][3] += e3 * u.w;
        }
    }
}

// ================= n2v projection (separate, high-occupancy) =================
__global__ __launch_bounds__(256) void k_n2vp_t(const float* __restrict__ n2v,
                                                const float* __restrict__ w,
                                                const float* __restrict__ b,
                                                float* __restrict__ n2vp) {
    __shared__ float As[64][AST2];
    __shared__ float W0[32 * 64];
    int nbase = blockIdx.x * 64;
    int tc = threadIdx.x & 15, tr = threadIdx.x >> 4;
    float acc[4][4] = {};
    for (int c = 0; c < 4; c++) {
        stageA32(n2v, nbase, EMBD, c * 32, As);
        stageW32(w + c * 32 * 64, W0);
        __syncthreads();
        mac8v(As, W0, acc, tr, tc);
        __syncthreads();
    }
    float b0 = b[tc * 4], b1 = b[tc * 4 + 1], b2 = b[tc * 4 + 2], b3 = b[tc * 4 + 3];
#pragma unroll
    for (int i = 0; i < 4; i++) {
        int row = nbase + tr * 4 + i;
        if (row < NN) {
            float4 o = {acc[i][0] + b0, acc[i][1] + b1, acc[i][2] + b2, acc[i][3] + b3};
            *(float4*)&n2vp[(size_t)row * HD + tc * 4] = o;
        }
    }
}

// ================= front: h0 = raw + sigmoid(gate) * delta =================
__global__ __launch_bounds__(256) void k_front_t(const float* __restrict__ x,
                                                 const float* __restrict__ n2vp,
                                                 const float* __restrict__ ip_w,
                                                 const float* __restrict__ ip_b,
                                                 const float* __restrict__ gate_w,
                                                 const float* __restrict__ gate_b,
                                                 float* __restrict__ h0) {
    __shared__ float As[64][AST2];
    __shared__ float W0[32 * 64];
    __shared__ float W1[32 * 64];
    int nbase = blockIdx.x * 64;
    int tc = threadIdx.x & 15, tr = threadIdx.x >> 4;
    float araw[4][4] = {}, ag[4][4] = {}, adel[4][4] = {};
    for (int c = 0; c < 8; c++) {
        stageA32(x, nbase, DIN, c * 32, As);
        stageW32(ip_w + c * 2048, W0);
        stageW32(gate_w + c * 2048, W1);
        __syncthreads();
        mac8v2(As, W0, W1, araw, ag, tr, tc);
        __syncthreads();
    }
    for (int c = 0; c < 2; c++) {
        stageA32(n2vp, nbase, HD, c * 32, As);
        stageW32(ip_w + (DIN + c * 32) * 64, W0);
        stageW32(gate_w + (DIN + c * 32) * 64, W1);
        __syncthreads();
        mac8v2(As, W0, W1, adel, ag, tr, tc);
        __syncthreads();
    }
    float ib0 = ip_b[tc * 4], ib1 = ip_b[tc * 4 + 1], ib2 = ip_b[tc * 4 + 2], ib3 = ip_b[tc * 4 + 3];
    float gb0 = gate_b[tc * 4], gb1 = gate_b[tc * 4 + 1], gb2 = gate_b[tc * 4 + 2], gb3 = gate_b[tc * 4 + 3];
#pragma unroll
    for (int i = 0; i < 4; i++) {
        int row = nbase + tr * 4 + i;
        if (row < NN) {
            float r0 = araw[i][0] + ib0, r1 = araw[i][1] + ib1, r2 = araw[i][2] + ib2, r3 = araw[i][3] + ib3;
            float s0 = 1.f / (1.f + __expf(-(ag[i][0] + gb0)));
            float s1 = 1.f / (1.f + __expf(-(ag[i][1] + gb1)));
            float s2 = 1.f / (1.f + __expf(-(ag[i][2] + gb2)));
            float s3 = 1.f / (1.f + __expf(-(ag[i][3] + gb3)));
            float4 o = {r0 + s0 * adel[i][0], r1 + s1 * adel[i][1],
                        r2 + s2 * adel[i][2], r3 + s3 * adel[i][3]};
            *(float4*)&h0[(size_t)row * HD + tc * 4] = o;
        }
    }
}

// ================= gather mean =================
__global__ void k_gather_mean(const int* __restrict__ rowptr, const int* __restrict__ colsrc,
                              const float* __restrict__ invdeg, const float* __restrict__ hin,
                              float* __restrict__ agg) {
    int t = threadIdx.x & 63;
    int gw = blockIdx.x * (blockDim.x >> 6) + (threadIdx.x >> 6);
    int stride = gridDim.x * (blockDim.x >> 6);
    for (int n = gw; n < NN; n += stride) {
        int bg = rowptr[n], en = rowptr[n + 1];
        float acc = 0.f;
        int i = bg;
        for (; i + 4 <= en; i += 4) {
            int s0 = colsrc[i], s1 = colsrc[i + 1], s2 = colsrc[i + 2], s3 = colsrc[i + 3];
            acc += hin[(size_t)s0 * HD + t] + hin[(size_t)s1 * HD + t] +
                   hin[(size_t)s2 * HD + t] + hin[(size_t)s3 * HD + t];
        }
        for (; i < en; i++) acc += hin[(size_t)colsrc[i] * HD + t];
        agg[(size_t)n * HD + t] = acc * invdeg[n];
    }
}

// ================= SAGE combine =================
__global__ __launch_bounds__(256) void k_sage_t(const float* __restrict__ agg,
                                                const float* __restrict__ h,
                                                const float* __restrict__ wl,
                                                const float* __restrict__ bl,
                                                const float* __restrict__ wr,
                                                float* __restrict__ hout) {
    __shared__ float As[64][AST2];
    __shared__ float W0[32 * 64];
    int nbase = blockIdx.x * 64;
    int tc = threadIdx.x & 15, tr = threadIdx.x >> 4;
    float acc[4][4] = {};
    for (int c = 0; c < 2; c++) {
        stageA32(agg, nbase, HD, c * 32, As);
        stageW32(wl + c * 2048, W0);
        __syncthreads();
        mac8v(As, W0, acc, tr, tc);
        __syncthreads();
    }
    for (int c = 0; c < 2; c++) {
        stageA32(h, nbase, HD, c * 32, As);
        stageW32(wr + c * 2048, W0);
        __syncthreads();
        mac8v(As, W0, acc, tr, tc);
        __syncthreads();
    }
    float b0 = bl[tc * 4], b1 = bl[tc * 4 + 1], b2 = bl[tc * 4 + 2], b3 = bl[tc * 4 + 3];
#pragma unroll
    for (int i = 0; i < 4; i++) {
        int row = nbase + tr * 4 + i;
        if (row < NN) {
            float4 o = {fmaxf(acc[i][0] + b0, 0.f), fmaxf(acc[i][1] + b1, 0.f),
                        fmaxf(acc[i][2] + b2, 0.f), fmaxf(acc[i][3] + b3, 0.f)};
            *(float4*)&hout[(size_t)row * HD + tc * 4] = o;
        }
    }
}

// ================= GAT transform =================
__global__ __launch_bounds__(256) void k_gatxh_t(const float* __restrict__ h,
                                                 const float* __restrict__ w,
                                                 const float* __restrict__ att_s,
                                                 const float* __restrict__ att_d,
                                                 float* __restrict__ xh,
                                                 float* __restrict__ a_s,
                                                 float* __restrict__ a_d) {
    __shared__ float As[64][AST2];
    __shared__ float W0[32 * 64];
    __shared__ float W1[32 * 64];
    int nbase = blockIdx.x * 64;
    int tc = threadIdx.x & 15, tr = threadIdx.x >> 4;
    float acc0[4][4] = {}, acc1[4][4] = {};
    for (int c = 0; c < 2; c++) {
        stageA32(h, nbase, HD, c * 32, As);
        stageW32cols(w + c * 32 * 128, 128, 0, W0);
        stageW32cols(w + c * 32 * 128, 128, 64, W1);
        __syncthreads();
        mac8v2(As, W0, W1, acc0, acc1, tr, tc);
        __syncthreads();
    }
#pragma unroll
    for (int half = 0; half < 2; half++) {
        float(*acc)[4] = half ? acc1 : acc0;
        float as0 = att_s[half * 64 + tc * 4], as1 = att_s[half * 64 + tc * 4 + 1];
        float as2 = att_s[half * 64 + tc * 4 + 2], as3 = att_s[half * 64 + tc * 4 + 3];
        float ad0 = att_d[half * 64 + tc * 4], ad1 = att_d[half * 64 + tc * 4 + 1];
        float ad2 = att_d[half * 64 + tc * 4 + 2], ad3 = att_d[half * 64 + tc * 4 + 3];
#pragma unroll
        for (int i = 0; i < 4; i++) {
            int row = nbase + tr * 4 + i;
            float ps = acc[i][0] * as0 + acc[i][1] * as1 + acc[i][2] * as2 + acc[i][3] * as3;
            float pd = acc[i][0] * ad0 + acc[i][1] * ad1 + acc[i][2] * ad2 + acc[i][3] * ad3;
#pragma unroll
            for (int off = 8; off; off >>= 1) {
                ps += __shfl_xor(ps, off);
                pd += __shfl_xor(pd, off);
            }
            if (row < NN) {
                *(float4*)&xh[(size_t)row * 128 + half * 64 + tc * 4] = *(float4*)&acc[i][0];
                if (tc == 0) {
                    a_s[row * 2 + half] = ps;
                    a_d[row * 2 + half] = pd;
                }
            }
        }
    }
}

// ================= GAT fused: single pass (no max-subtraction; math-identical) =================
__global__ void k_gat_fused(const int* __restrict__ rowptr, const int* __restrict__ colsrc,
                            const float* __restrict__ a_s, const float* __restrict__ a_d,
                            const float* __restrict__ xh, const float* __restrict__ gb,
                            float* __restrict__ hout) {
    int t = threadIdx.x & 63;
    float bias = gb[t];
    int gw = blockIdx.x * (blockDim.x >> 6) + (threadIdx.x >> 6);
    int stride = gridDim.x * (blockDim.x >> 6);
    for (int n = gw; n < NN; n += stride) {
        int bg = rowptr[n], en = rowptr[n + 1];
        float ad0 = a_d[n * 2], ad1 = a_d[n * 2 + 1];
        float ws0 = __expf(lrelu(a_s[n * 2] + ad0));
        float ws1 = __expf(lrelu(a_s[n * 2 + 1] + ad1));
        float s0 = ws0, s1 = ws1;
        float acc0 = ws0 * xh[(size_t)n * 128 + t];
        float acc1 = ws1 * xh[(size_t)n * 128 + 64 + t];
        int i = bg;
        for (; i + 2 <= en; i += 2) {
            int sa = colsrc[i], sb = colsrc[i + 1];
            float wa0 = __expf(lrelu(a_s[sa * 2] + ad0));
            float wa1 = __expf(lrelu(a_s[sa * 2 + 1] + ad1));
            float wb0 = __expf(lrelu(a_s[sb * 2] + ad0));
            float wb1 = __expf(lrelu(a_s[sb * 2 + 1] + ad1));
            float xa0 = xh[(size_t)sa * 128 + t], xa1 = xh[(size_t)sa * 128 + 64 + t];
            float xb0 = xh[(size_t)sb * 128 + t], xb1 = xh[(size_t)sb * 128 + 64 + t];
            s0 += wa0 + wb0;
            s1 += wa1 + wb1;
            acc0 += wa0 * xa0 + wb0 * xb0;
            acc1 += wa1 * xa1 + wb1 * xb1;
        }
        for (; i < en; i++) {
            int s = colsrc[i];
            float w0 = __expf(lrelu(a_s[s * 2] + ad0));
            float w1 = __expf(lrelu(a_s[s * 2 + 1] + ad1));
            s0 += w0;
            s1 += w1;
            acc0 += w0 * xh[(size_t)s * 128 + t];
            acc1 += w1 * xh[(size_t)s * 128 + 64 + t];
        }
        float r0 = 0.5f / (s0 + 1e-16f), r1 = 0.5f / (s1 + 1e-16f);
        hout[(size_t)n * HD + t] = fmaxf(acc0 * r0 + acc1 * r1 + bias, 0.f);
    }
}

// ================= final SAGE =================
__global__ void k_pfin(const float* __restrict__ h, const float* __restrict__ wl,
                       float* __restrict__ P) {
    __shared__ float sw[HD * OUTD];
    for (int i = threadIdx.x; i < HD * OUTD; i += blockDim.x) sw[i] = wl[i];
    __syncthreads();
    int t = threadIdx.x & 63;
    int c = t & 31, half = t >> 5;
    int gw = blockIdx.x * (blockDim.x >> 6) + (threadIdx.x >> 6);
    int stride = gridDim.x * (blockDim.x >> 6);
    for (int n = gw; n < NN; n += stride) {
        float hv = h[(size_t)n * HD + t];
        float acc = 0.f;
#pragma unroll 8
        for (int i = 0; i < 32; i++) {
            float bb = __shfl(hv, half * 32 + i);
            acc += bb * sw[half * 1024 + i * 32 + c];
        }
        acc += __shfl_xor(acc, 32);
        if (half == 0) P[(size_t)n * OUTD + c] = acc;
    }
}

__global__ void k_final_fused(const int* __restrict__ rowptr, const int* __restrict__ colsrc,
                              const float* __restrict__ invdeg, const float* __restrict__ P,
                              const float* __restrict__ h, const float* __restrict__ bl,
                              const float* __restrict__ wr, float* __restrict__ out) {
    __shared__ float sw[HD * OUTD];
    for (int i = threadIdx.x; i < HD * OUTD; i += blockDim.x) sw[i] = wr[i];
    __syncthreads();
    int t = threadIdx.x & 63;
    int j = t & 31, half = t >> 5;
    float bias = bl[j];
    int gw = blockIdx.x * (blockDim.x >> 6) + (threadIdx.x >> 6);
    int stride = gridDim.x * (blockDim.x >> 6);
    for (int n = gw; n < NN; n += stride) {
        int bg = rowptr[n], en = rowptr[n + 1];
        float acc = 0.f;
        for (int i = bg + half; i < en; i += 2) acc += P[(size_t)colsrc[i] * OUTD + j];
        acc += __shfl_xor(acc, 32);
        float hv = h[(size_t)n * HD + t];
        float o = 0.f;
#pragma unroll 8
        for (int i2 = 0; i2 < 32; i2++) {
            float bb = __shfl(hv, half * 32 + i2);
            o += bb * sw[half * 1024 + i2 * 32 + j];
        }
        o += __shfl_xor(o, 32);
        if (half == 0) out[(size_t)n * OUTD + j] = acc * invdeg[n] + bias + o;
    }
}

// ================= launch =================
extern "C" void kernel_launch(void* const* d_in, const int* in_sizes, int n_in,
                              void* d_out, int out_size, void* d_ws, size_t ws_size,
                              hipStream_t stream) {
    const float* x      = (const float*)d_in[0];
    const int*   eidx   = (const int*)d_in[1];
    const float* n2v    = (const float*)d_in[2];
    const float* n2v_w  = (const float*)d_in[3];
    const float* n2v_b  = (const float*)d_in[4];
    const float* ip_w   = (const float*)d_in[5];
    const float* ip_b   = (const float*)d_in[6];
    const float* gate_w = (const float*)d_in[7];
    const float* gate_b = (const float*)d_in[8];
    const float* s0_wl  = (const float*)d_in[9];
    const float* s0_bl  = (const float*)d_in[10];
    const float* s0_wr  = (const float*)d_in[11];
    const float* s1_wl  = (const float*)d_in[12];
    const float* s1_bl  = (const float*)d_in[13];
    const float* s1_wr  = (const float*)d_in[14];
    const float* gat_w  = (const float*)d_in[15];
    const float* att_s  = (const float*)d_in[16];
    const float* att_d  = (const float*)d_in[17];
    const float* gat_b  = (const float*)d_in[18];
    const float* f_wl   = (const float*)d_in[19];
    const float* f_bl   = (const float*)d_in[20];
    const float* f_wr   = (const float*)d_in[21];

    const int* src = eidx;
    const int* dst = eidx + NE;

    // ---- workspace ----
    float* ws     = (float*)d_ws;
    float* invdeg = ws;                        // N
    float* S1     = invdeg + NN;               // 64N
    float* S2     = S1 + (size_t)NN * HD;      // 64N
    float* S4     = S2 + (size_t)NN * HD;      // 128N: [agg | n2vp] then xh
    float* a_s    = S4 + (size_t)NN * 128;     // 2N
    float* a_d    = a_s + (size_t)NN * 2;      // 2N
    float* P      = a_d + (size_t)NN * 2;      // 32N
    int*   cnt    = (int*)(P + (size_t)NN * OUTD);
    int*   rowptr = cnt + NN;
    int*   cursor = rowptr + NN + 1;
    int*   blksum = cursor + NN;               // 128
    int*   colsrc = blksum + 128;              // NE

    float* agg  = S4;
    float* n2vp = S4 + (size_t)NN * HD;
    float* xh   = S4;
    float* out  = (float*)d_out;

    const int BT = 256;
    dim3 b128(128), b256(BT);
    int eblk = (NE + BT - 1) / BT;
    int nblk = (NN + BT - 1) / BT;

    // ---- CSR ----
    hipMemsetAsync(cnt, 0, (size_t)NN * 4, stream);
    k_count<<<eblk, b256, 0, stream>>>(dst, cnt);
    k_scan1<<<SNBLK, b256, 0, stream>>>(cnt, rowptr, blksum);
    k_scan2<<<1, b128, 0, stream>>>(blksum);
    k_scan3<<<nblk, b256, 0, stream>>>(blksum, cnt, rowptr, cursor, invdeg);
    k_fill<<<eblk, b256, 0, stream>>>(src, dst, cursor, colsrc);

    // ---- front ----
    k_n2vp_t<<<NT, b256, 0, stream>>>(n2v, n2v_w, n2v_b, n2vp);
    k_front_t<<<NT, b256, 0, stream>>>(x, n2vp, ip_w, ip_b, gate_w, gate_b, S2);

    // ---- SAGE 0: S2 -> S1 ----
    k_gather_mean<<<2048, b256, 0, stream>>>(rowptr, colsrc, invdeg, S2, agg);
    k_sage_t<<<NT, b256, 0, stream>>>(agg, S2, s0_wl, s0_bl, s0_wr, S1);

    // ---- SAGE 1: S1 -> S2 ----
    k_gather_mean<<<2048, b256, 0, stream>>>(rowptr, colsrc, invdeg, S1, agg);
    k_sage_t<<<NT, b256, 0, stream>>>(agg, S1, s1_wl, s1_bl, s1_wr, S2);

    // ---- GAT: S2 -> S1 ----
    k_gatxh_t<<<NT, b256, 0, stream>>>(S2, gat_w, att_s, att_d, xh, a_s, a_d);
    k_gat_fused<<<2048, b256, 0, stream>>>(rowptr, colsrc, a_s, a_d, xh, gat_b, S1);

    // ---- final SAGE: S1 -> out ----
    k_pfin<<<2048, b256, 0, stream>>>(S1, f_wl, P);
    k_final_fused<<<2048, b256, 0, stream>>>(rowptr, colsrc, invdeg, P, S1, f_bl, f_wr, out);
}